// Round 5
// baseline (2555.441 us; speedup 1.0000x reference)
//
#include <hip/hip_runtime.h>
#include <hip/hip_bf16.h>
#include <stdint.h>
#include <stddef.h>

// Problem constants (B=32, T=256, E=H=1024)
#define TT    256
#define NBLK  128   // 64 layer0 blocks + 64 layer1 blocks, 4 waves each

typedef __attribute__((ext_vector_type(8))) short short8;
typedef __attribute__((ext_vector_type(4))) float f32x4;

// fp32 -> bf16 (RNE)
__device__ __forceinline__ short f2bf(float v) {
  uint32_t u = __builtin_bit_cast(uint32_t, v);
  uint32_t r = (u + 0x7fffu + ((u >> 16) & 1u)) >> 16;
  return (short)r;
}

// Direct global->LDS 16B stage. COH: CPol SC0|SC1 (=1|16) -> bypass L1/L2,
// read MALL (coherent with producer's sc0sc1 write-through stores).
__device__ __forceinline__ void stage_coh(const short8* g, short8* l) {
  __builtin_amdgcn_global_load_lds(
      (const __attribute__((address_space(1))) void*)g,
      (__attribute__((address_space(3))) void*)l, 16, 0, 17);
}
__device__ __forceinline__ void stage_pln(const short8* g, short8* l) {
  __builtin_amdgcn_global_load_lds(
      (const __attribute__((address_space(1))) void*)g,
      (__attribute__((address_space(3))) void*)l, 16, 0, 0);
}

// Poll 16 barrier lines (lane i -> line i&15): lanes 0-31 check baseA>=tgtA,
// lanes 32-63 check baseB>=tgtB. Lines are 128B apart, RMW density 4/line/step.
__device__ __forceinline__ void spin_lines(const uint32_t* baseA, uint32_t tgtA,
                                           const uint32_t* baseB, uint32_t tgtB,
                                           int lane) {
  const uint32_t* p = (lane < 32 ? baseA : baseB) + (lane & 15) * 32;
  const uint32_t tgt = (lane < 32) ? tgtA : tgtB;
  for (;;) {
    uint32_t v = __hip_atomic_load(p, __ATOMIC_RELAXED, __HIP_MEMORY_SCOPE_AGENT);
    if (__all(v >= tgt)) break;
    __builtin_amdgcn_s_sleep(1);
  }
}

// ---------------------------------------------------------------------------
// K0: mask passthrough output; zero h0-ring slot 127 + h1 ping-pong + barrier
// counters (contiguous 204800B region at ws+58654720).
// ---------------------------------------------------------------------------
__global__ void k_init(const float* __restrict__ mask, float* __restrict__ out,
                       uint32_t* __restrict__ z) {
  int tid = blockIdx.x * blockDim.x + threadIdx.x;   // 16384 threads
  if (tid < 8192) out[8388608 + tid] = mask[tid];
  for (int j = tid; j < 51200; j += 16384) z[j] = 0; // 64KB+128KB+8KB
}

// ---------------------------------------------------------------------------
// K1: pack weights into bf16 MFMA-B fragment order.
// Bp[wgid 0..511][f 0..63][lane 0..63][8 shorts], wgid = layer*256 + blk*4 + w
//  f = cg*16 + s;  k = w*512 + s*32 + (lane>>4)*8 + j  (B-frag: n=lane&15)
//  col = ((lane&15)>>2)*1024 + blk*16 + cg*4 + (lane&3)   (gate-interleaved)
// ---------------------------------------------------------------------------
__global__ void k_packw(const float* __restrict__ Wih0, const float* __restrict__ Whh0,
                        const float* __restrict__ Wih1, const float* __restrict__ Whh1,
                        short* __restrict__ Bp) {
  int cid = blockIdx.x * blockDim.x + threadIdx.x;   // 0 .. 2097151
  int l    = cid & 63;
  int f    = (cid >> 6) & 63;
  int wgid = cid >> 12;                               // 0..511
  int q  = l >> 4, cc = l & 15;
  int cg = f >> 4, s = f & 15;
  int w    = wgid & 3;
  int blk  = (wgid >> 2) & 63;
  bool p1  = (wgid >= 256);
  int precol = (cc >> 2) * 1024 + blk * 16 + cg * 4 + (cc & 3);
  const float* MA = p1 ? Wih1 : Wih0;
  const float* MB = p1 ? Whh1 : Whh0;
  short8 o;
#pragma unroll
  for (int j = 0; j < 8; ++j) {
    int k = w * 512 + s * 32 + q * 8 + j;            // 0..2047
    const float* M = (k < 1024) ? MA : MB;
    o[j] = f2bf(M[(size_t)(k & 1023) * 4096 + precol]);
  }
  ((short8*)Bp)[cid] = o;
}

// ---------------------------------------------------------------------------
// K2: convert x to bf16 blocked A-layout per t: Xb[t][kb][m=b][8]
// ---------------------------------------------------------------------------
__global__ void k_packx(const float* __restrict__ x, short* __restrict__ Xb) {
  int tid = blockIdx.x * blockDim.x + threadIdx.x;   // 0 .. 1048575
  int eg = tid & 127;
  int t  = (tid >> 7) & 255;
  int b  = tid >> 15;
  const float* src = x + ((size_t)(b * 256 + t) * 1024 + eg * 8);
  short8 o;
#pragma unroll
  for (int j = 0; j < 8; ++j) o[j] = f2bf(src[j]);
  ((short8*)Xb)[(t * 128 + eg) * 32 + b] = o;
}

// ---------------------------------------------------------------------------
// K3: persistent recurrent kernel. 128 blocks x 256 threads (4 waves).
// bid<64 -> layer0, bid>=64 -> layer1. R4 staging core kept (global_load_lds,
// aux=17 coherent for h panels / 0 for Xb; h store dwordx4 sc0sc1).
//
// R5 CHANGES (barrier restructure):
//  * SINGLE-LEVEL barrier: per layer 16 cumulative counter lines (128B
//    apart, 4 blocks each). Arrival = wave0 tid0 fetch_add AFTER vmcnt(0)
//    drain of its h store. Spinners poll the 16 lines directly
//    (lane i&15 -> line, __all(v>=4t)). Removes master+epoch = 2 RTTs.
//  * WAVE-SPECIALIZED waiting at loop TOP (t>=1):
//      l0 wv0/1 (Xb source):   never wait
//      l0 wv2/3 (h0 source):   l0 lines >= 4t; ring-WAR: l1 >= 4(t-126) @t>=127
//      l1 wv0/1 (h0 source):   l0 lines >= 4t   (pre-satisfied when trailing)
//      l1 wv2/3 (h1 source):   l1 lines >= 4t
//    Non-waiting waves run ahead into step t's staging+MFMA while the
//    publish chain completes, meeting at sync#1.
//  * 2 barriers/step: sync#1 (xch write->read), sync#2 (xch read->next
//    write + hstage write->wave0 read). xch un-overlaid (packed [4][3],
//    24KB; LDS total 153KB) so the R4 sync#0 is gone.
// Safety: arrivals are cumulative (max 1024, no wrap); intra-layer skew <=1
// step; writer-side hazards (h1 ping-pong WAR, h0 ring WAR) gated
// transitively through wv2/3's spin + sync#1/#2 before wave0's store.
// ---------------------------------------------------------------------------
__global__ __launch_bounds__(256, 1) void k_lstm(
    const float* __restrict__ mask, const float* __restrict__ b0,
    const float* __restrict__ b1,   const short* __restrict__ Bp,
    const short* __restrict__ Xb,   short* __restrict__ h0r,
    short* __restrict__ h1b,        float* __restrict__ out,
    uint32_t* bar) {
  __shared__ short8 stg[8192];          // 128KB: 4 waves x 32KB A-halves
  __shared__ f32x4 xch[4][3][2][64];    // 24KB packed partial-sum exchange
  __shared__ short hstage[512];         // 1KB h repack staging

  const int tid  = threadIdx.x;
  const int wv   = tid >> 6;          // wave 0..3 (K-slice)
  const int lane = tid & 63;
  const int quad = lane >> 4;
  const int cc   = lane & 15;
  const int bid  = blockIdx.x;
  const bool is1 = (bid >= 64);
  const int blk  = bid & 63;
  const int wgid = (is1 ? 256 : 0) + blk * 4 + wv;
  const int n0w  = blk * 16 + wv * 4;             // h-col base for gating
  const int hcol = n0w + (cc & 3);
  const int kb0  = (wv & 1) * 64;                 // kb offset within source panel
  const bool coh = !(!is1 && wv < 2);             // this wave's A-source is an h panel

  uint32_t* const lines0 = bar;          // l0 lines: +j*32, j<16
  uint32_t* const lines1 = bar + 1024;   // l1 lines
  uint32_t* const arrC   = (is1 ? lines1 : lines0) + (blk & 15) * 32;

  // B fragments (64 KB) resident in registers
  short8 bfr[64];
  {
    const short8* pB = ((const short8*)Bp) + (size_t)wgid * 4096 + lane;
#pragma unroll
    for (int f = 0; f < 64; ++f) bfr[f] = pB[f * 64];
  }
  const float* bias = is1 ? b1 : b0;
  const float bv = bias[(cc >> 2) * 1024 + n0w + (cc & 3)];

  float cst[8], hst[8];
#pragma unroll
  for (int i = 0; i < 8; ++i) { cst[i] = 0.f; hst[i] = 0.f; }

  const int shuf_base = (lane & 48) | (lane & 3);
  const short8* Xq = (const short8*)Xb;
  const short8* H0 = (const short8*)h0r;
  const short8* H1 = (const short8*)h1b;

  short8* const ldsW = stg + wv * 2048;           // this wave's staging base

  // layer0's h0(255) is consumed by nobody -> it stops after step 254.
  const int tmax = is1 ? TT : (TT - 1);

  for (int t = 0; t < tmax; ++t) {
    const int p  = t & 1;              // h1 ping-pong read parity; write 1-p
    const int rs = (t + 127) & 127;    // h0 ring read slot = (t-1) mod 128

    const short8* pan;
    if (!is1) pan = (wv < 2) ? (Xq + (size_t)t * 4096) : (H0 + (size_t)rs * 4096);
    else      pan = (wv < 2) ? (H0 + (size_t)rs * 4096) : (H1 + p * 4096);

    float mrow[8];
#pragma unroll
    for (int i = 0; i < 8; ++i) {
      int r = ((i >> 2) << 4) + quad * 4 + (i & 3);
      mrow[i] = mask[r * 256 + t];
    }

    // ---- wave-specialized readiness wait (loop top) ----
    if (t > 0) {
      const uint32_t tgt = (uint32_t)(4 * t);
      if (!is1) {
        if (wv >= 2) {
          uint32_t tgtB = (t >= 127) ? (uint32_t)(4 * (t - 126)) : 0u;
          spin_lines(lines0, tgt, lines1, tgtB, lane);   // own + ring-WAR
        }
      } else {
        if (wv < 2) spin_lines(lines0, tgt, lines0, tgt, lane);  // h0 ready
        else        spin_lines(lines1, tgt, lines1, tgt, lane);  // h1 ready
      }
    }

    // ---- stage this wave's 32KB A-half into LDS (register-free DMA) ----
    {
      const short8* gsrc = pan + kb0 * 32 + lane;  // per-lane global source
      if (coh) {
#pragma unroll
        for (int i = 0; i < 32; ++i) stage_coh(gsrc + i * 64, ldsW + i * 64);
      } else {
#pragma unroll
        for (int i = 0; i < 32; ++i) stage_pln(gsrc + i * 64, ldsW + i * 64);
      }
      asm volatile("s_waitcnt vmcnt(0)" ::: "memory");
      __builtin_amdgcn_sched_barrier(0);
    }

    f32x4 acc[4][2];
#pragma unroll
    for (int cg = 0; cg < 4; ++cg) { acc[cg][0] = (f32x4)0.f; acc[cg][1] = (f32x4)0.f; }

#pragma unroll
    for (int s = 0; s < 16; ++s) {
      short8 a0 = ldsW[(s * 4 + quad) * 32 + cc];        // rows 0..15
      short8 a1 = ldsW[(s * 4 + quad) * 32 + cc + 16];   // rows 16..31
#pragma unroll
      for (int cg = 0; cg < 4; ++cg) {
        acc[cg][0] = __builtin_amdgcn_mfma_f32_16x16x32_bf16(a0, bfr[cg * 16 + s], acc[cg][0], 0, 0, 0);
        acc[cg][1] = __builtin_amdgcn_mfma_f32_16x16x32_bf16(a1, bfr[cg * 16 + s], acc[cg][1], 0, 0, 0);
      }
    }

    // ---- cross-wave K-reduction via packed LDS xch ----
#pragma unroll
    for (int cg = 0; cg < 4; ++cg) {
      if (cg != wv) {
        int slot = cg < wv ? cg : cg - 1;
        xch[wv][slot][0][lane] = acc[cg][0];
        xch[wv][slot][1][lane] = acc[cg][1];
      }
    }
    __syncthreads();   // sync#1: xch writes -> reads
    f32x4 s0 = acc[wv][0], s1 = acc[wv][1];
#pragma unroll
    for (int w2 = 0; w2 < 4; ++w2) {
      if (w2 != wv) {
        int slot = wv < w2 ? wv : wv - 1;
        s0 += xch[w2][slot][0][lane];
        s1 += xch[w2][slot][1][lane];
      }
    }

    float pv[8];
    pv[0] = s0.x + bv; pv[1] = s0.y + bv; pv[2] = s0.z + bv; pv[3] = s0.w + bv;
    pv[4] = s1.x + bv; pv[5] = s1.y + bv; pv[6] = s1.z + bv; pv[7] = s1.w + bv;

    // ---- gating (C/D: col = lane&15, row = quad*4 + reg) ----
#pragma unroll
    for (int i = 0; i < 8; ++i) {
      float v = pv[i];
      float fg = __shfl(v, shuf_base + 0, 64);
      float ig = __shfl(v, shuf_base + 4, 64);
      float og = __shfl(v, shuf_base + 8, 64);
      float gg = __shfl(v, shuf_base + 12, 64);
      int r = ((i >> 2) << 4) + quad * 4 + (i & 3);
      float m  = mrow[i];
      float om = 1.f - m;
      float sf = 1.f / (1.f + __expf(-fg));
      float si = 1.f / (1.f + __expf(-ig));
      float so = 1.f / (1.f + __expf(-og));
      float e2 = __expf(-2.f * fabsf(gg));
      float tg = (1.f - e2) / (1.f + e2);
      tg = (gg < 0.f) ? -tg : tg;
      float c1 = sf * cst[i] + si * tg;
      c1 = c1 * m + cst[i] * om;
      float ec = __expf(-2.f * fabsf(c1));
      float tc = (1.f - ec) / (1.f + ec);
      tc = (c1 < 0.f) ? -tc : tc;
      float h1 = so * tc;
      h1 = h1 * m + hst[i] * om;
      cst[i] = c1; hst[i] = h1;
      if ((lane & 12) == 0) {   // gate-f lanes: one writer per (h-col, row)
        int hl = wv * 4 + (cc & 3);                 // block-local h-col 0..15
        hstage[(hl >> 3) * 256 + r * 8 + (hl & 7)] = f2bf(h1);
        if (is1) out[((size_t)r * 256 + t) * 1024 + hcol] = h1;
      }
    }

    if (is1 && t == TT - 1) break;   // layer1 final step: no successor

    __syncthreads();   // sync#2: hstage ready; also guards xch reuse (reads
                       // of step t done before step t+1 writes by any wave)
    if (wv == 0) {     // packed MALL write-through h store: 16B/lane, 1 op
      short* dst = (is1 ? (h1b + (1 - p) * 32768)
                        : (h0r + (t & 127) * 32768)) + blk * 512 + lane * 8;
      short8 hv = ((const short8*)hstage)[lane];
      asm volatile("global_store_dwordx4 %0, %1, off sc0 sc1"
                   :: "v"(dst), "v"(hv) : "memory");
      if (lane == 0) {
        // drain this wave's h stores to MALL, then make arrival observable
        asm volatile("s_waitcnt vmcnt(0)" ::: "memory");
        __hip_atomic_fetch_add(arrC, 1u, __ATOMIC_RELAXED, __HIP_MEMORY_SCOPE_AGENT);
      }
    }
    // no loop-end barrier: waves proceed; dependent waves wait at loop top,
    // all waves re-converge at sync#1 of step t+1.
  }
}

// ---------------------------------------------------------------------------
// Workspace layout (bytes):
//   [0, 32MB)            B_packed (512 waves x 64KB bf16)
//   [32MB, 48MB)         X blocked
//   [48MB, 56MB)         h0 ring: 128 slots x 64KB (slot = t & 127)
//   [56MB, 56MB+128KB)   h1 ping-pong (2 x 64KB)
//   [+8KB)               barrier (per layer: 16 cumulative lines, 128B apart)
//   k_init zeroes [56MB-64KB, 56MB+136KB) = ring slot 127 + h1 + counters
// ---------------------------------------------------------------------------
extern "C" void kernel_launch(void* const* d_in, const int* in_sizes, int n_in,
                              void* d_out, int out_size, void* d_ws, size_t ws_size,
                              hipStream_t stream) {
  const float* x    = (const float*)d_in[0];
  const float* mask = (const float*)d_in[1];
  const float* Wih0 = (const float*)d_in[2];
  const float* Whh0 = (const float*)d_in[3];
  const float* b0   = (const float*)d_in[4];
  const float* Wih1 = (const float*)d_in[5];
  const float* Whh1 = (const float*)d_in[6];
  const float* b1   = (const float*)d_in[7];
  float* out = (float*)d_out;

  char* ws = (char*)d_ws;
  short*    Bp  = (short*)ws;
  short*    Xb  = (short*)(ws + 33554432);
  short*    h0r = (short*)(ws + 50331648);
  short*    h1b = (short*)(ws + 58720256);
  uint32_t* bar = (uint32_t*)(ws + 58851328);
  uint32_t* z   = (uint32_t*)(ws + 58654720);   // zero region base

  hipLaunchKernelGGL(k_init,  dim3(64),   dim3(256), 0, stream, mask, out, z);
  hipLaunchKernelGGL(k_packw, dim3(8192), dim3(256), 0, stream, Wih0, Whh0, Wih1, Whh1, Bp);
  hipLaunchKernelGGL(k_packx, dim3(4096), dim3(256), 0, stream, x, Xb);
  hipLaunchKernelGGL(k_lstm,  dim3(NBLK), dim3(256), 0, stream,
                     mask, b0, b1, Bp, Xb, h0r, h1b, out, bar);
}

// Round 6
// 2475.463 us; speedup vs baseline: 1.0323x; 1.0323x over previous
//
#include <hip/hip_runtime.h>
#include <hip/hip_bf16.h>
#include <stdint.h>
#include <stddef.h>

// Problem constants (B=32, T=256, E=H=1024)
#define TT    256
#define NBLK  128   // 64 layer0 blocks + 64 layer1 blocks, 4 waves each

typedef __attribute__((ext_vector_type(8))) short short8;
typedef __attribute__((ext_vector_type(4))) float f32x4;

// fp32 -> bf16 (RNE)
__device__ __forceinline__ short f2bf(float v) {
  uint32_t u = __builtin_bit_cast(uint32_t, v);
  uint32_t r = (u + 0x7fffu + ((u >> 16) & 1u)) >> 16;
  return (short)r;
}

// Direct global->LDS 16B stage, normally cached (L1+L2). Freshness of h
// panels is guaranteed by ring addressing + scheduled agent-acquire fences
// (see k_lstm header), NOT by cache bypass.
__device__ __forceinline__ void stage16(const short8* g, short8* l) {
  __builtin_amdgcn_global_load_lds(
      (const __attribute__((address_space(1))) void*)g,
      (__attribute__((address_space(3))) void*)l, 16, 0, 0);
}

// Poll 16 barrier lines (lane i -> line i&15): lanes 0-31 check baseA>=tgtA,
// lanes 32-63 check baseB>=tgtB. MALL-coherent relaxed atomic loads.
__device__ __forceinline__ void spin_lines(const uint32_t* baseA, uint32_t tgtA,
                                           const uint32_t* baseB, uint32_t tgtB,
                                           int lane) {
  const uint32_t* p = (lane < 32 ? baseA : baseB) + (lane & 15) * 32;
  const uint32_t tgt = (lane < 32) ? tgtA : tgtB;
  for (;;) {
    uint32_t v = __hip_atomic_load(p, __ATOMIC_RELAXED, __HIP_MEMORY_SCOPE_AGENT);
    if (__all(v >= tgt)) break;
    __builtin_amdgcn_s_sleep(1);
  }
}

// ---------------------------------------------------------------------------
// K0: mask passthrough; zero h0-ring slot 127, h1-ring slot 31, barrier block.
// wsu = (uint32_t*)ws. Offsets (uints): h0 slot127 @14663680, h1 slot31
// @15187968 (64KB each = 16384 uints), bar @15204352 (8KB).
// ---------------------------------------------------------------------------
__global__ void k_init(const float* __restrict__ mask, float* __restrict__ out,
                       uint32_t* __restrict__ wsu) {
  int tid = blockIdx.x * blockDim.x + threadIdx.x;   // 16384 threads
  if (tid < 8192) out[8388608 + tid] = mask[tid];
  wsu[14663680 + tid] = 0;                  // h0 ring slot 127 (h0(-1)=0)
  wsu[15187968 + tid] = 0;                  // h1 ring slot 31  (h1(-1)=0)
  if (tid < 2048) wsu[15204352 + tid] = 0;  // barrier lines
}

// ---------------------------------------------------------------------------
// K1: pack weights into bf16 MFMA-B fragment order.
// Bp[wgid 0..511][f 0..63][lane 0..63][8 shorts], wgid = layer*256 + blk*4 + w
//  f = cg*16 + s;  k = w*512 + s*32 + (lane>>4)*8 + j  (B-frag: n=lane&15)
//  col = ((lane&15)>>2)*1024 + blk*16 + cg*4 + (lane&3)   (gate-interleaved)
// ---------------------------------------------------------------------------
__global__ void k_packw(const float* __restrict__ Wih0, const float* __restrict__ Whh0,
                        const float* __restrict__ Wih1, const float* __restrict__ Whh1,
                        short* __restrict__ Bp) {
  int cid = blockIdx.x * blockDim.x + threadIdx.x;   // 0 .. 2097151
  int l    = cid & 63;
  int f    = (cid >> 6) & 63;
  int wgid = cid >> 12;                               // 0..511
  int q  = l >> 4, cc = l & 15;
  int cg = f >> 4, s = f & 15;
  int w    = wgid & 3;
  int blk  = (wgid >> 2) & 63;
  bool p1  = (wgid >= 256);
  int precol = (cc >> 2) * 1024 + blk * 16 + cg * 4 + (cc & 3);
  const float* MA = p1 ? Wih1 : Wih0;
  const float* MB = p1 ? Whh1 : Whh0;
  short8 o;
#pragma unroll
  for (int j = 0; j < 8; ++j) {
    int k = w * 512 + s * 32 + q * 8 + j;            // 0..2047
    const float* M = (k < 1024) ? MA : MB;
    o[j] = f2bf(M[(size_t)(k & 1023) * 4096 + precol]);
  }
  ((short8*)Bp)[cid] = o;
}

// ---------------------------------------------------------------------------
// K2: convert x to bf16 blocked A-layout per t: Xb[t][kb][m=b][8]
// ---------------------------------------------------------------------------
__global__ void k_packx(const float* __restrict__ x, short* __restrict__ Xb) {
  int tid = blockIdx.x * blockDim.x + threadIdx.x;   // 0 .. 1048575
  int eg = tid & 127;
  int t  = (tid >> 7) & 255;
  int b  = tid >> 15;
  const float* src = x + ((size_t)(b * 256 + t) * 1024 + eg * 8);
  short8 o;
#pragma unroll
  for (int j = 0; j < 8; ++j) o[j] = f2bf(src[j]);
  ((short8*)Xb)[(t * 128 + eg) * 32 + b] = o;
}

// ---------------------------------------------------------------------------
// K3: persistent recurrent kernel. 128 blocks x 256 threads (4 waves).
// bid<64 -> layer0, bid>=64 -> layer1. Sync skeleton = R5 (16-line cumulative
// barrier per layer, wave-specialized waits, 2 intra-block barriers/step).
//
// R6 CHANGE — h panels read via NORMAL CACHED loads (aux=0) so the ~16
// blocks per XCD share one L2 fill per line. R4/R5 issued 12MB/step of
// sc0sc1 MALL reads (196K line-requests bursting after flag-detect ->
// multi-us MALL queue tail, the dominant step cost; invisible in
// FETCH_SIZE). Now coherent-read traffic drops ~8x.
// Correctness WITHOUT per-step invalidation (R3's mistake):
//  * producers still store h with sc0sc1 write-through -> MALL always fresh;
//  * consumers read a ROTATING address: h0 = 128-slot ring (existing),
//    h1 = 32-slot ring (new). A slot address is re-read only after >=32
//    steps;
//  * agent-acquire fence (buffer_inv: invalidates clean L1+L2) at steps
//    (t&31)==1 -> any cached line dies between consecutive uses of the same
//    address (max fence gap 32 <= min reuse distance 32; fence@f sits after
//    step f-1's reads and before step f's). 8 fences/run, ~us total cost.
//  * cross-layer: l0 leads l1 by <=126 steps (ring gate) < 128 -> l0 and l1
//    never touch the same h0 slot address with different versions.
//  * cross-dispatch staleness handled by the dispatch-boundary acquire
//    (same mechanism all prior rounds relied on for k_init visibility).
// Flag polls/arrivals stay MALL-coherent relaxed atomics (must bypass L2).
// ---------------------------------------------------------------------------
__global__ __launch_bounds__(256, 1) void k_lstm(
    const float* __restrict__ mask, const float* __restrict__ b0,
    const float* __restrict__ b1,   const short* __restrict__ Bp,
    const short* __restrict__ Xb,   short* __restrict__ h0r,
    short* __restrict__ h1b,        float* __restrict__ out,
    uint32_t* bar) {
  __shared__ short8 stg[8192];          // 128KB: 4 waves x 32KB A-halves
  __shared__ f32x4 xch[4][3][2][64];    // 24KB packed partial-sum exchange
  __shared__ short hstage[512];         // 1KB h repack staging

  const int tid  = threadIdx.x;
  const int wv   = tid >> 6;          // wave 0..3 (K-slice)
  const int lane = tid & 63;
  const int quad = lane >> 4;
  const int cc   = lane & 15;
  const int bid  = blockIdx.x;
  const bool is1 = (bid >= 64);
  const int blk  = bid & 63;
  const int wgid = (is1 ? 256 : 0) + blk * 4 + wv;
  const int n0w  = blk * 16 + wv * 4;             // h-col base for gating
  const int hcol = n0w + (cc & 3);
  const int kb0  = (wv & 1) * 64;                 // kb offset within source panel

  uint32_t* const lines0 = bar;          // l0 lines: +j*32, j<16
  uint32_t* const lines1 = bar + 1024;   // l1 lines
  uint32_t* const arrC   = (is1 ? lines1 : lines0) + (blk & 15) * 32;

  // B fragments (64 KB) resident in registers
  short8 bfr[64];
  {
    const short8* pB = ((const short8*)Bp) + (size_t)wgid * 4096 + lane;
#pragma unroll
    for (int f = 0; f < 64; ++f) bfr[f] = pB[f * 64];
  }
  const float* bias = is1 ? b1 : b0;
  const float bv = bias[(cc >> 2) * 1024 + n0w + (cc & 3)];

  float cst[8], hst[8];
#pragma unroll
  for (int i = 0; i < 8; ++i) { cst[i] = 0.f; hst[i] = 0.f; }

  const int shuf_base = (lane & 48) | (lane & 3);
  const short8* Xq = (const short8*)Xb;
  const short8* H0 = (const short8*)h0r;
  const short8* H1 = (const short8*)h1b;

  short8* const ldsW = stg + wv * 2048;           // this wave's staging base

  // layer0's h0(255) is consumed by nobody -> it stops after step 254.
  const int tmax = is1 ? TT : (TT - 1);

  for (int t = 0; t < tmax; ++t) {
    const int p  = t & 31;             // h1 ring write slot
    const int rs = (t + 127) & 127;    // h0 ring read slot = (t-1) mod 128
    const int r1 = (t + 31) & 31;      // h1 ring read slot = (t-1) mod 32

    const short8* pan;
    if (!is1) pan = (wv < 2) ? (Xq + (size_t)t * 4096) : (H0 + (size_t)rs * 4096);
    else      pan = (wv < 2) ? (H0 + (size_t)rs * 4096) : (H1 + (size_t)r1 * 4096);

    float mrow[8];
#pragma unroll
    for (int i = 0; i < 8; ++i) {
      int r = ((i >> 2) << 4) + quad * 4 + (i & 3);
      mrow[i] = mask[r * 256 + t];
    }

    // ---- wave-specialized readiness wait (loop top) ----
    if (t > 0) {
      const uint32_t tgt = (uint32_t)(4 * t);
      if (!is1) {
        if (wv >= 2) {
          uint32_t tgtB = (t >= 127) ? (uint32_t)(4 * (t - 126)) : 0u;
          spin_lines(lines0, tgt, lines1, tgtB, lane);   // own + ring-WAR
        }
      } else {
        if (wv < 2) spin_lines(lines0, tgt, lines0, tgt, lane);  // h0 ready
        else        spin_lines(lines1, tgt, lines1, tgt, lane);  // h1 ready
      }
    }

    // ---- scheduled L1/L2 invalidate (8x per run): bounds cached-line age
    //      below the minimum ring reuse distance (32 steps) ----
    if ((t & 31) == 1) __builtin_amdgcn_fence(__ATOMIC_ACQUIRE, "agent");

    // ---- stage this wave's 32KB A-half into LDS (register-free DMA,
    //      normally cached: XCD siblings share L2 fills) ----
    {
      const short8* gsrc = pan + kb0 * 32 + lane;  // per-lane global source
#pragma unroll
      for (int i = 0; i < 32; ++i) stage16(gsrc + i * 64, ldsW + i * 64);
      asm volatile("s_waitcnt vmcnt(0)" ::: "memory");
      __builtin_amdgcn_sched_barrier(0);
    }

    f32x4 acc[4][2];
#pragma unroll
    for (int cg = 0; cg < 4; ++cg) { acc[cg][0] = (f32x4)0.f; acc[cg][1] = (f32x4)0.f; }

#pragma unroll
    for (int s = 0; s < 16; ++s) {
      short8 a0 = ldsW[(s * 4 + quad) * 32 + cc];        // rows 0..15
      short8 a1 = ldsW[(s * 4 + quad) * 32 + cc + 16];   // rows 16..31
#pragma unroll
      for (int cg = 0; cg < 4; ++cg) {
        acc[cg][0] = __builtin_amdgcn_mfma_f32_16x16x32_bf16(a0, bfr[cg * 16 + s], acc[cg][0], 0, 0, 0);
        acc[cg][1] = __builtin_amdgcn_mfma_f32_16x16x32_bf16(a1, bfr[cg * 16 + s], acc[cg][1], 0, 0, 0);
      }
    }

    // ---- cross-wave K-reduction via packed LDS xch ----
#pragma unroll
    for (int cg = 0; cg < 4; ++cg) {
      if (cg != wv) {
        int slot = cg < wv ? cg : cg - 1;
        xch[wv][slot][0][lane] = acc[cg][0];
        xch[wv][slot][1][lane] = acc[cg][1];
      }
    }
    __syncthreads();   // sync#1: xch writes -> reads
    f32x4 s0 = acc[wv][0], s1 = acc[wv][1];
#pragma unroll
    for (int w2 = 0; w2 < 4; ++w2) {
      if (w2 != wv) {
        int slot = wv < w2 ? wv : wv - 1;
        s0 += xch[w2][slot][0][lane];
        s1 += xch[w2][slot][1][lane];
      }
    }

    float pv[8];
    pv[0] = s0.x + bv; pv[1] = s0.y + bv; pv[2] = s0.z + bv; pv[3] = s0.w + bv;
    pv[4] = s1.x + bv; pv[5] = s1.y + bv; pv[6] = s1.z + bv; pv[7] = s1.w + bv;

    // ---- gating (C/D: col = lane&15, row = quad*4 + reg) ----
#pragma unroll
    for (int i = 0; i < 8; ++i) {
      float v = pv[i];
      float fg = __shfl(v, shuf_base + 0, 64);
      float ig = __shfl(v, shuf_base + 4, 64);
      float og = __shfl(v, shuf_base + 8, 64);
      float gg = __shfl(v, shuf_base + 12, 64);
      int r = ((i >> 2) << 4) + quad * 4 + (i & 3);
      float m  = mrow[i];
      float om = 1.f - m;
      float sf = 1.f / (1.f + __expf(-fg));
      float si = 1.f / (1.f + __expf(-ig));
      float so = 1.f / (1.f + __expf(-og));
      float e2 = __expf(-2.f * fabsf(gg));
      float tg = (1.f - e2) / (1.f + e2);
      tg = (gg < 0.f) ? -tg : tg;
      float c1 = sf * cst[i] + si * tg;
      c1 = c1 * m + cst[i] * om;
      float ec = __expf(-2.f * fabsf(c1));
      float tc = (1.f - ec) / (1.f + ec);
      tc = (c1 < 0.f) ? -tc : tc;
      float h1 = so * tc;
      h1 = h1 * m + hst[i] * om;
      cst[i] = c1; hst[i] = h1;
      if ((lane & 12) == 0) {   // gate-f lanes: one writer per (h-col, row)
        int hl = wv * 4 + (cc & 3);                 // block-local h-col 0..15
        hstage[(hl >> 3) * 256 + r * 8 + (hl & 7)] = f2bf(h1);
        if (is1) out[((size_t)r * 256 + t) * 1024 + hcol] = h1;
      }
    }

    if (is1 && t == TT - 1) break;   // layer1 final step: no successor

    __syncthreads();   // sync#2: hstage ready; also guards xch reuse
    if (wv == 0) {     // packed MALL write-through h store: 16B/lane, 1 op
      short* dst = (is1 ? (h1b + (size_t)p * 32768)
                        : (h0r + (size_t)(t & 127) * 32768)) + blk * 512 + lane * 8;
      short8 hv = ((const short8*)hstage)[lane];
      asm volatile("global_store_dwordx4 %0, %1, off sc0 sc1"
                   :: "v"(dst), "v"(hv) : "memory");
      if (lane == 0) {
        // drain this wave's h stores to MALL, then make arrival observable
        asm volatile("s_waitcnt vmcnt(0)" ::: "memory");
        __hip_atomic_fetch_add(arrC, 1u, __ATOMIC_RELAXED, __HIP_MEMORY_SCOPE_AGENT);
      }
    }
    // no loop-end barrier: waves proceed; dependent waves wait at loop top,
    // all waves re-converge at sync#1 of step t+1.
  }
}

// ---------------------------------------------------------------------------
// Workspace layout (bytes):
//   [0, 32MB)            B_packed (512 waves x 64KB bf16)
//   [32MB, 48MB)         X blocked
//   [48MB, 56MB)         h0 ring: 128 slots x 64KB (slot = t & 127)
//   [56MB, 58MB)         h1 ring:  32 slots x 64KB (slot = t & 31)
//   [58MB, 58MB+8KB)     barrier (per layer: 16 cumulative lines, 128B apart)
// ---------------------------------------------------------------------------
extern "C" void kernel_launch(void* const* d_in, const int* in_sizes, int n_in,
                              void* d_out, int out_size, void* d_ws, size_t ws_size,
                              hipStream_t stream) {
  const float* x    = (const float*)d_in[0];
  const float* mask = (const float*)d_in[1];
  const float* Wih0 = (const float*)d_in[2];
  const float* Whh0 = (const float*)d_in[3];
  const float* b0   = (const float*)d_in[4];
  const float* Wih1 = (const float*)d_in[5];
  const float* Whh1 = (const float*)d_in[6];
  const float* b1   = (const float*)d_in[7];
  float* out = (float*)d_out;

  char* ws = (char*)d_ws;
  short*    Bp  = (short*)ws;
  short*    Xb  = (short*)(ws + 33554432);
  short*    h0r = (short*)(ws + 50331648);
  short*    h1b = (short*)(ws + 58720256);
  uint32_t* bar = (uint32_t*)(ws + 60817408);

  hipLaunchKernelGGL(k_init,  dim3(64),   dim3(256), 0, stream, mask, out, (uint32_t*)ws);
  hipLaunchKernelGGL(k_packw, dim3(8192), dim3(256), 0, stream, Wih0, Whh0, Wih1, Whh1, Bp);
  hipLaunchKernelGGL(k_packx, dim3(4096), dim3(256), 0, stream, x, Xb);
  hipLaunchKernelGGL(k_lstm,  dim3(NBLK), dim3(256), 0, stream,
                     mask, b0, b1, Bp, Xb, h0r, h1b, out, bar);
}